// Round 10
// baseline (267.411 us; speedup 1.0000x reference)
//
#include <hip/hip_runtime.h>
#include <stdint.h>

#define NPIX 4096
#define CDIM 512

typedef _Float16 hv8 __attribute__((ext_vector_type(8)));
typedef float f32x4 __attribute__((ext_vector_type(4)));

__device__ __forceinline__ void lds_direct16(const _Float16* g, _Float16* l) {
    __builtin_amdgcn_global_load_lds(
        (const __attribute__((address_space(1))) void*)g,
        (__attribute__((address_space(3))) void*)l, 16, 0, 0);
}

// ---------------- weight fp32 -> fp16 ----------------
__global__ void cvt_w(const float* __restrict__ s0, const float* __restrict__ s1,
                      const float* __restrict__ s2, const float* __restrict__ s3,
                      _Float16* __restrict__ d0, _Float16* __restrict__ d1,
                      _Float16* __restrict__ d2, _Float16* __restrict__ d3) {
    int i = blockIdx.x * 256 + threadIdx.x;
    d0[i] = (_Float16)s0[i];
    d1[i] = (_Float16)s1[i];
    d2[i] = (_Float16)s2[i];
    d3[i] = (_Float16)s3[i];
}

// ---------------- groupnorm stats: one block per (b,g) ----------------
__global__ void stats_kernel(const float* __restrict__ x, float* __restrict__ stats) {
    int idx = blockIdx.x;
    const float4* base = (const float4*)(x + (long)idx * 16 * NPIX);
    int tid = threadIdx.x;
    float s = 0.f, sq = 0.f;
    for (int it = 0; it < 64; ++it) {
        float4 f = base[it * 256 + tid];
        s  += f.x + f.y + f.z + f.w;
        sq += f.x * f.x + f.y * f.y + f.z * f.z + f.w * f.w;
    }
    __shared__ float rs[256], rq[256];
    rs[tid] = s; rq[tid] = sq;
    __syncthreads();
    for (int st = 128; st > 0; st >>= 1) {
        if (tid < st) { rs[tid] += rs[tid + st]; rq[tid] += rq[tid + st]; }
        __syncthreads();
    }
    if (tid == 0) {
        float mean = rs[0] * (1.0f / 65536.0f);
        float var  = rq[0] * (1.0f / 65536.0f) - mean * mean;
        stats[idx * 2]     = mean;
        stats[idx * 2 + 1] = rsqrtf(var + 1e-6f);
    }
}

// ---------------- normalize + transpose: hT[b][n][c] = GN(x)[b][c][n] ----------------
__global__ void normT_kernel(const float* __restrict__ x, const float* __restrict__ stats,
                             const float* __restrict__ gamma, const float* __restrict__ beta,
                             _Float16* __restrict__ hT) {
    int b = blockIdx.z, c0 = blockIdx.x * 32, n0 = blockIdx.y * 32;
    int tid = threadIdx.x;
    __shared__ float t[32][33];
    int cl = tid >> 5;
    int nl = tid & 31;
    for (int r = 0; r < 4; ++r)
        t[r * 8 + cl][nl] = x[(long)b * CDIM * NPIX + (long)(c0 + r * 8 + cl) * NPIX + n0 + nl];
    __syncthreads();
    for (int r = 0; r < 4; ++r) {
        int nr = r * 8 + cl;
        int c = c0 + nl;
        float m    = stats[(b * 32 + (c >> 4)) * 2];
        float rstd = stats[(b * 32 + (c >> 4)) * 2 + 1];
        float val = (t[nl][nr] - m) * rstd * gamma[c] + beta[c];
        hT[(long)b * NPIX * CDIM + (long)(n0 + nr) * CDIM + c] = (_Float16)val;
    }
}

// ---------------- bt-form GEMM: D[M][N] = A[M][K] * BT[N][K]^T ----------------
template<int EPI>
__launch_bounds__(256, 2)
__global__ void gemm_bt_kernel(const _Float16* __restrict__ A, const _Float16* __restrict__ BT,
                               void* __restrict__ D, const float* __restrict__ bias,
                               const float* __restrict__ resid,
                               int M, int N, int K,
                               long aBatch, long bBatch, long dBatch, long rBatch) {
    const int b = blockIdx.z;
    A  += (long)b * aBatch;
    BT += (long)b * bBatch;
    const int m0 = blockIdx.y * 128;
    const int n0 = blockIdx.x * 128;
    const int tid = threadIdx.x;
    const int l = tid & 63;
    const int w = tid >> 6;
    const int wm = (w >> 1) * 64;
    const int wn = (w & 1) * 64;
    const int lr = l & 15;
    const int lk = l >> 4;
    __shared__ __align__(16) _Float16 As[128 * 32];
    __shared__ __align__(16) _Float16 Bs[128 * 32];
    f32x4 acc[4][4] = {};
    const int nK = K >> 5;
    for (int kt = 0; kt < nK; ++kt) {
        const int kb = kt * 32;
#pragma unroll
        for (int c = 0; c < 2; ++c) {
            int chunk = c * 256 + tid;
            int row = chunk >> 2;
            int k8 = (chunk & 3) * 8;
            _Float16* ldsA = As + (size_t)(c * 256 + (tid & ~63)) * 8;
            _Float16* ldsB = Bs + (size_t)(c * 256 + (tid & ~63)) * 8;
            lds_direct16(A  + (long)(m0 + row) * K + kb + k8, ldsA);
            lds_direct16(BT + (long)(n0 + row) * K + kb + k8, ldsB);
        }
        __syncthreads();
        hv8 af[4], bfr[4];
#pragma unroll
        for (int mi = 0; mi < 4; ++mi)
            af[mi] = *(const hv8*)(As + (size_t)(wm + mi * 16 + lr) * 32 + lk * 8);
#pragma unroll
        for (int ni = 0; ni < 4; ++ni)
            bfr[ni] = *(const hv8*)(Bs + (size_t)(wn + ni * 16 + lr) * 32 + lk * 8);
#pragma unroll
        for (int mi = 0; mi < 4; ++mi)
#pragma unroll
            for (int ni = 0; ni < 4; ++ni)
                acc[mi][ni] = __builtin_amdgcn_mfma_f32_16x16x32_f16(af[mi], bfr[ni], acc[mi][ni], 0, 0, 0);
        __syncthreads();
    }
#pragma unroll
    for (int mi = 0; mi < 4; ++mi)
#pragma unroll
        for (int ni = 0; ni < 4; ++ni)
#pragma unroll
            for (int r = 0; r < 4; ++r) {
                int row = m0 + wm + mi * 16 + lk * 4 + r;
                int col = n0 + wn + ni * 16 + lr;
                float val = acc[mi][ni][r];
                if (EPI == 0) {
                    ((_Float16*)D)[(long)b * dBatch + (long)row * N + col] = (_Float16)(val + bias[col]);
                } else if (EPI == 1) {
                    ((_Float16*)D)[(long)b * dBatch + (long)row * N + col] = (_Float16)(val + bias[row]);
                } else {
                    long idx = (long)row * N + col;
                    ((float*)D)[(long)b * dBatch + idx] =
                        val + bias[row] + resid[(long)b * rBatch + idx];
                }
            }
}

// ---------------- flash attention v10 ----------------
// i-tile 32, j-tile 64, j-split 2, grid 512 (2 rounds), XCD pinning.
// Wave grid iq(2) x jq(4): each K-row read by only 2 waves (half the LDS K-read
// of v8). K double-buffered in LDS via global_load_lds. V in REGISTERS,
// double-buffered, loaded AFTER PV consumes the old set (WAR-safe) with counted
// vmcnt(8) at the end barrier -> ~1.5-step latency window, zero LDS cost.
// ps stride 144 B: 16 mod 128 walks all 8 bank groups over 8 rows -> conflict-free.
// One barrier per step (PV deferred one step, parity-disjoint ps).
__launch_bounds__(512, 2)
__global__ void attn_kernel(const _Float16* __restrict__ qT, const _Float16* __restrict__ kT,
                            const _Float16* __restrict__ v,
                            _Float16* __restrict__ p0, _Float16* __restrict__ p1,
                            float* __restrict__ lbuf) {
    __shared__ __align__(16) _Float16 Ks[2][64 * 512];   // 128 KB, rows 1 KB, XOR (j&7)<<4
    __shared__ __align__(16) char ps[2][32 * 144];       // 9 KB, 144 B rows (conflict-free)
    __shared__ float red[8][32];
    __shared__ float redt[32];

    const int g = blockIdx.x;                        // 0..511
    const int xcd = g & 7;
    const int comb = xcd >> 1;                       // (batch, jhalf)
    const int itile = ((g >> 3) << 1) | (xcd & 1);   // 0..127
    const int batch = comb >> 1;
    const int jhalf = comb & 1;
    const int i0 = itile * 32;
    const int jbase = jhalf * 2048;

    const int tid = threadIdx.x;
    const int l = tid & 63, w = tid >> 6;
    const int lr = l & 15, lk = l >> 4;
    const int iq = w >> 2, jq = w & 3;               // QK: rows iq*16, cols jq*16 (of 64)

    const _Float16* qb = qT + (long)batch * NPIX * CDIM;
    const _Float16* kb = kT + (long)batch * NPIX * CDIM;
    const _Float16* vb = v  + (long)batch * CDIM * NPIX;

    // Q fragments: rows i0 + iq*16 + lr, all 16 k-chunks (64 VGPR)
    hv8 af[16];
    {
        const _Float16* qr = qb + (long)(i0 + iq * 16 + lr) * CDIM + lk * 8;
#pragma unroll
        for (int kk = 0; kk < 16; ++kk)
            af[kk] = *(const hv8*)(qr + kk * 32);
    }

    f32x4 oacc[2][4] = {};   // rows mi*16+lk*4+r (32), cols w*64+ni*16+lr
    float lsum[4] = {};
    hv8 vfA[4][2], vfB[4][2];

    const _Float16* vptr = vb + (long)(w * 64 + lr) * NPIX + jbase + lk * 8;
    const float scale = 0.044194173824159216f;   // 1/sqrt(512)

// stage K tile JT (64 rows) into Ks[BUF]; 8 instrs/thread, source col pre-swizzled
#define STAGE(BUF, JT)                                                               \
    {                                                                                \
        const long j0s = (long)jbase + (JT) * 64;                                    \
        _Float16* kd = Ks[BUF];                                                      \
        _Pragma("unroll")                                                            \
        for (int q = 0; q < 8; ++q) {                                                \
            int row = q * 8 + w;                                                     \
            int cc = l ^ (row & 7);                                                  \
            lds_direct16(kb + (j0s + row) * CDIM + cc * 8, kd + row * 512);          \
        }                                                                            \
    }

// load V fragments for tile JT into VF (wave-unique c-range w*64; 8 loads)
#define VLOAD(VF, JT)                                                                \
    {                                                                                \
        _Pragma("unroll")                                                            \
        for (int ni = 0; ni < 4; ++ni)                                               \
            _Pragma("unroll")                                                        \
            for (int jh = 0; jh < 2; ++jh)                                           \
                VF[ni][jh] = *(const hv8*)(vptr + (long)ni * (16 * NPIX) + (JT) * 64 + jh * 32); \
    }

// QK(JT) -> exp -> ps[CUR]; wave tile rows iq*16, cols jq*16 of 64
#define QKEXP(CUR)                                                                   \
    {                                                                                \
        const char* kbase = (const char*)Ks[CUR];                                    \
        f32x4 sa = {}, sb = {};                                                      \
        const int jj = jq * 16 + lr;                                                 \
        const uint32_t sw = (uint32_t)((jj & 7) << 4);                               \
        _Pragma("unroll")                                                            \
        for (int kk = 0; kk < 8; ++kk) {                                             \
            hv8 b0 = *(const hv8*)(kbase + (((uint32_t)(jj * 1024 + (2 * kk) * 64 + lk * 16)) ^ sw));     \
            sa = __builtin_amdgcn_mfma_f32_16x16x32_f16(af[2 * kk], b0, sa, 0, 0, 0);                     \
            hv8 b1 = *(const hv8*)(kbase + (((uint32_t)(jj * 1024 + (2 * kk + 1) * 64 + lk * 16)) ^ sw)); \
            sb = __builtin_amdgcn_mfma_f32_16x16x32_f16(af[2 * kk + 1], b1, sb, 0, 0, 0);                 \
        }                                                                            \
        sa += sb;                                                                    \
        _Pragma("unroll")                                                            \
        for (int r = 0; r < 4; ++r) {                                                \
            float p = __expf(sa[r] * scale);                                         \
            lsum[r] += p;                                                            \
            int i = iq * 16 + lk * 4 + r;                                            \
            int j2 = jq * 16 + lr;                                                   \
            *(_Float16*)(ps[CUR] + i * 144 + j2 * 2) = (_Float16)p;                  \
        }                                                                            \
    }

// PV of the PREVIOUS step: ps[PRV] (32 rows x 64 j) x VF
#define PVSTEP(PRV, VF)                                                              \
    {                                                                                \
        _Pragma("unroll")                                                            \
        for (int jk = 0; jk < 2; ++jk) {                                             \
            hv8 pa[2];                                                               \
            _Pragma("unroll")                                                        \
            for (int mi = 0; mi < 2; ++mi) {                                         \
                int i2 = mi * 16 + lr;                                               \
                pa[mi] = *(const hv8*)(ps[PRV] + i2 * 144 + jk * 64 + lk * 16);      \
            }                                                                        \
            _Pragma("unroll")                                                        \
            for (int ni = 0; ni < 4; ++ni)                                           \
                _Pragma("unroll")                                                    \
                for (int mi = 0; mi < 2; ++mi)                                       \
                    oacc[mi][ni] = __builtin_amdgcn_mfma_f32_16x16x32_f16(pa[mi], VF[ni][jk], oacc[mi][ni], 0, 0, 0); \
        }                                                                            \
    }

// counted end barrier: V(t+1)'s 8 loads stay in flight; K(t+1) + V(t) retired
#define ENDBAR(N)                                                                    \
    __builtin_amdgcn_sched_barrier(0);                                               \
    asm volatile("s_waitcnt vmcnt(" #N ") lgkmcnt(0)" ::: "memory");                 \
    __builtin_amdgcn_s_barrier();                                                    \
    __builtin_amdgcn_sched_barrier(0);

// CUR = compile-time parity of JT. VF = set holding V(JT-1): consumed by PV,
// then refilled with V(JT+1) (same parity).
#define STEP(JT, CUR, VF)                                                            \
    {                                                                                \
        if ((JT) < 31) STAGE((CUR) ^ 1, (JT) + 1)                                    \
        __builtin_amdgcn_sched_barrier(0);                                           \
        __builtin_amdgcn_s_setprio(1);                                               \
        QKEXP(CUR)                                                                   \
        PVSTEP((CUR) ^ 1, VF)                                                        \
        __builtin_amdgcn_s_setprio(0);                                               \
        if ((JT) < 31) VLOAD(VF, (JT) + 1)                                           \
        ENDBAR(8)                                                                    \
    }

    // prologue: K0 + V0; wait K0 (V0 in flight)
    STAGE(0, 0)
    VLOAD(vfA, 0)
    __builtin_amdgcn_sched_barrier(0);
    asm volatile("s_waitcnt vmcnt(8)" ::: "memory");
    __builtin_amdgcn_s_barrier();
    __builtin_amdgcn_sched_barrier(0);

    // step 0: no PV yet
    STAGE(1, 1)
    __builtin_amdgcn_s_setprio(1);
    QKEXP(0)
    __builtin_amdgcn_s_setprio(0);
    VLOAD(vfB, 1)
    ENDBAR(8)

    // steady: steps 1..30 in pairs, then 31
    for (int jt = 1; jt < 31; jt += 2) {
        STEP(jt,     1, vfA)
        STEP(jt + 1, 0, vfB)
    }
    STEP(31, 1, vfA)

    // epilogue: PV(31) with V(31) (set B) -- drain the last V loads first
    asm volatile("s_waitcnt vmcnt(0)" ::: "memory");
    __builtin_amdgcn_sched_barrier(0);
    PVSTEP(1, vfB)

    // ---- row-sum reduce: over lr (16 lanes), then over the 4 jq waves ----
#pragma unroll
    for (int m = 1; m <= 8; m <<= 1)
#pragma unroll
        for (int r = 0; r < 4; ++r)
            lsum[r] += __shfl_xor(lsum[r], m, 64);
    if (lr == 0)
#pragma unroll
        for (int r = 0; r < 4; ++r)
            red[w][iq * 16 + lk * 4 + r] = lsum[r];
    __syncthreads();
    if (tid < 32) {
        int iqq = tid >> 4;
        float lv = red[iqq * 4 + 0][tid] + red[iqq * 4 + 1][tid]
                 + red[iqq * 4 + 2][tid] + red[iqq * 4 + 3][tid];
        redt[tid] = 1.0f / lv;
        lbuf[jhalf * 8192 + batch * NPIX + i0 + tid] = lv;
    }
    __syncthreads();

    // ---- store normalized per-half partial O (fp16) ----
    _Float16* dsth = (jhalf ? p1 : p0) + (long)batch * NPIX * CDIM;
#pragma unroll
    for (int mi = 0; mi < 2; ++mi)
#pragma unroll
        for (int r = 0; r < 4; ++r) {
            int row = mi * 16 + lk * 4 + r;
            float rv = redt[row];
#pragma unroll
            for (int ni = 0; ni < 4; ++ni) {
                int c = w * 64 + ni * 16 + lr;
                dsth[(long)(i0 + row) * CDIM + c] = (_Float16)(oacc[mi][ni][r] * rv);
            }
        }
#undef STEP
#undef ENDBAR
#undef PVSTEP
#undef QKEXP
#undef VLOAD
#undef STAGE
}

// ---------------- combine: out = (O0*l0 + O1*l1) / (l0+l1) ----------------
__global__ void combine_kernel(const _Float16* __restrict__ p0, const _Float16* __restrict__ p1,
                               const float* __restrict__ lbuf, _Float16* __restrict__ out) {
    long g = (long)blockIdx.x * 256 + threadIdx.x;
    long base = g * 8;
    int rowg = (int)(g >> 6);                 // b*4096 + n
    float l0 = lbuf[rowg], l1 = lbuf[8192 + rowg];
    float w0 = l0 / (l0 + l1);
    float w1 = 1.0f - w0;
    hv8 a = *(const hv8*)(p0 + base);
    hv8 b = *(const hv8*)(p1 + base);
    hv8 o;
#pragma unroll
    for (int i = 0; i < 8; ++i)
        o[i] = (_Float16)((float)a[i] * w0 + (float)b[i] * w1);
    *(hv8*)(out + base) = o;
}

extern "C" void kernel_launch(void* const* d_in, const int* in_sizes, int n_in,
                              void* d_out, int out_size, void* d_ws, size_t ws_size,
                              hipStream_t stream) {
    const float* x     = (const float*)d_in[0];
    const float* gamma = (const float*)d_in[1];
    const float* beta  = (const float*)d_in[2];
    const float* wq    = (const float*)d_in[3];
    const float* bq    = (const float*)d_in[4];
    const float* wk    = (const float*)d_in[5];
    const float* bk    = (const float*)d_in[6];
    const float* wv    = (const float*)d_in[7];
    const float* bv    = (const float*)d_in[8];
    const float* wo    = (const float*)d_in[9];
    const float* bo    = (const float*)d_in[10];
    float* out = (float*)d_out;

    char* ws = (char*)d_ws;
    float* stats = (float*)ws;
    _Float16* wqb = (_Float16*)(ws + 1024);
    _Float16* wkb = wqb + 262144;
    _Float16* wvb = wkb + 262144;
    _Float16* wob = wvb + 262144;
    _Float16* hT  = wob + 262144;
    const long TSZ = (long)2 * NPIX * CDIM;
    _Float16* qT = hT + TSZ;
    _Float16* kT = qT + TSZ;
    _Float16* vv = kT + TSZ;
    _Float16* oT = vv + TSZ;
    float* lbuf = (float*)(oT + TSZ);        // 2 halves x 8192 rows

    cvt_w<<<dim3(1024), dim3(256), 0, stream>>>(wq, wk, wv, wo, wqb, wkb, wvb, wob);
    stats_kernel<<<dim3(64), dim3(256), 0, stream>>>(x, stats);
    normT_kernel<<<dim3(16, 128, 2), dim3(256), 0, stream>>>(x, stats, gamma, beta, hT);

    const long NC = (long)NPIX * CDIM;
    gemm_bt_kernel<0><<<dim3(4, 32, 2), dim3(256), 0, stream>>>(
        hT, wqb, (void*)qT, bq, nullptr, NPIX, CDIM, CDIM, NC, 0L, NC, 0L);
    gemm_bt_kernel<0><<<dim3(4, 32, 2), dim3(256), 0, stream>>>(
        hT, wkb, (void*)kT, bk, nullptr, NPIX, CDIM, CDIM, NC, 0L, NC, 0L);
    gemm_bt_kernel<1><<<dim3(32, 4, 2), dim3(256), 0, stream>>>(
        wvb, hT, (void*)vv, bv, nullptr, CDIM, NPIX, CDIM, 0L, NC, NC, 0L);

    // attention: partial jhalf0 -> oT, jhalf1 -> hT (dead), sums -> lbuf
    attn_kernel<<<dim3(512), dim3(512), 0, stream>>>(qT, kT, vv, oT, hT, lbuf);

    // combine halves into qT (dead after attn)
    combine_kernel<<<dim3(2048), dim3(256), 0, stream>>>(oT, hT, lbuf, qT);

    gemm_bt_kernel<2><<<dim3(32, 4, 2), dim3(256), 0, stream>>>(
        wob, qT, (void*)out, bo, x, CDIM, NPIX, CDIM, 0L, NC, NC, NC);
}

// Round 11
// 191.925 us; speedup vs baseline: 1.3933x; 1.3933x over previous
//
#include <hip/hip_runtime.h>
#include <stdint.h>

#define NPIX 4096
#define CDIM 512

typedef _Float16 hv8 __attribute__((ext_vector_type(8)));
typedef float f32x4 __attribute__((ext_vector_type(4)));

__device__ __forceinline__ void lds_direct16(const _Float16* g, _Float16* l) {
    __builtin_amdgcn_global_load_lds(
        (const __attribute__((address_space(1))) void*)g,
        (__attribute__((address_space(3))) void*)l, 16, 0, 0);
}

// ---------------- weight fp32 -> fp16 ----------------
__global__ void cvt_w(const float* __restrict__ s0, const float* __restrict__ s1,
                      const float* __restrict__ s2, const float* __restrict__ s3,
                      _Float16* __restrict__ d0, _Float16* __restrict__ d1,
                      _Float16* __restrict__ d2, _Float16* __restrict__ d3) {
    int i = blockIdx.x * 256 + threadIdx.x;
    d0[i] = (_Float16)s0[i];
    d1[i] = (_Float16)s1[i];
    d2[i] = (_Float16)s2[i];
    d3[i] = (_Float16)s3[i];
}

// ---------------- groupnorm stats: one block per (b,g) ----------------
__global__ void stats_kernel(const float* __restrict__ x, float* __restrict__ stats) {
    int idx = blockIdx.x;
    const float4* base = (const float4*)(x + (long)idx * 16 * NPIX);
    int tid = threadIdx.x;
    float s = 0.f, sq = 0.f;
    for (int it = 0; it < 64; ++it) {
        float4 f = base[it * 256 + tid];
        s  += f.x + f.y + f.z + f.w;
        sq += f.x * f.x + f.y * f.y + f.z * f.z + f.w * f.w;
    }
    __shared__ float rs[256], rq[256];
    rs[tid] = s; rq[tid] = sq;
    __syncthreads();
    for (int st = 128; st > 0; st >>= 1) {
        if (tid < st) { rs[tid] += rs[tid + st]; rq[tid] += rq[tid + st]; }
        __syncthreads();
    }
    if (tid == 0) {
        float mean = rs[0] * (1.0f / 65536.0f);
        float var  = rq[0] * (1.0f / 65536.0f) - mean * mean;
        stats[idx * 2]     = mean;
        stats[idx * 2 + 1] = rsqrtf(var + 1e-6f);
    }
}

// ---------------- normalize + transpose: hT[b][n][c] = GN(x)[b][c][n] ----------------
__global__ void normT_kernel(const float* __restrict__ x, const float* __restrict__ stats,
                             const float* __restrict__ gamma, const float* __restrict__ beta,
                             _Float16* __restrict__ hT) {
    int b = blockIdx.z, c0 = blockIdx.x * 32, n0 = blockIdx.y * 32;
    int tid = threadIdx.x;
    __shared__ float t[32][33];
    int cl = tid >> 5;
    int nl = tid & 31;
    for (int r = 0; r < 4; ++r)
        t[r * 8 + cl][nl] = x[(long)b * CDIM * NPIX + (long)(c0 + r * 8 + cl) * NPIX + n0 + nl];
    __syncthreads();
    for (int r = 0; r < 4; ++r) {
        int nr = r * 8 + cl;
        int c = c0 + nl;
        float m    = stats[(b * 32 + (c >> 4)) * 2];
        float rstd = stats[(b * 32 + (c >> 4)) * 2 + 1];
        float val = (t[nl][nr] - m) * rstd * gamma[c] + beta[c];
        hT[(long)b * NPIX * CDIM + (long)(n0 + nr) * CDIM + c] = (_Float16)val;
    }
}

// ---------------- bt-form GEMM: D[M][N] = A[M][K] * BT[N][K]^T ----------------
template<int EPI>
__launch_bounds__(256, 2)
__global__ void gemm_bt_kernel(const _Float16* __restrict__ A, const _Float16* __restrict__ BT,
                               void* __restrict__ D, const float* __restrict__ bias,
                               const float* __restrict__ resid,
                               int M, int N, int K,
                               long aBatch, long bBatch, long dBatch, long rBatch) {
    const int b = blockIdx.z;
    A  += (long)b * aBatch;
    BT += (long)b * bBatch;
    const int m0 = blockIdx.y * 128;
    const int n0 = blockIdx.x * 128;
    const int tid = threadIdx.x;
    const int l = tid & 63;
    const int w = tid >> 6;
    const int wm = (w >> 1) * 64;
    const int wn = (w & 1) * 64;
    const int lr = l & 15;
    const int lk = l >> 4;
    __shared__ __align__(16) _Float16 As[128 * 32];
    __shared__ __align__(16) _Float16 Bs[128 * 32];
    f32x4 acc[4][4] = {};
    const int nK = K >> 5;
    for (int kt = 0; kt < nK; ++kt) {
        const int kb = kt * 32;
#pragma unroll
        for (int c = 0; c < 2; ++c) {
            int chunk = c * 256 + tid;
            int row = chunk >> 2;
            int k8 = (chunk & 3) * 8;
            _Float16* ldsA = As + (size_t)(c * 256 + (tid & ~63)) * 8;
            _Float16* ldsB = Bs + (size_t)(c * 256 + (tid & ~63)) * 8;
            lds_direct16(A  + (long)(m0 + row) * K + kb + k8, ldsA);
            lds_direct16(BT + (long)(n0 + row) * K + kb + k8, ldsB);
        }
        __syncthreads();
        hv8 af[4], bfr[4];
#pragma unroll
        for (int mi = 0; mi < 4; ++mi)
            af[mi] = *(const hv8*)(As + (size_t)(wm + mi * 16 + lr) * 32 + lk * 8);
#pragma unroll
        for (int ni = 0; ni < 4; ++ni)
            bfr[ni] = *(const hv8*)(Bs + (size_t)(wn + ni * 16 + lr) * 32 + lk * 8);
#pragma unroll
        for (int mi = 0; mi < 4; ++mi)
#pragma unroll
            for (int ni = 0; ni < 4; ++ni)
                acc[mi][ni] = __builtin_amdgcn_mfma_f32_16x16x32_f16(af[mi], bfr[ni], acc[mi][ni], 0, 0, 0);
        __syncthreads();
    }
#pragma unroll
    for (int mi = 0; mi < 4; ++mi)
#pragma unroll
        for (int ni = 0; ni < 4; ++ni)
#pragma unroll
            for (int r = 0; r < 4; ++r) {
                int row = m0 + wm + mi * 16 + lk * 4 + r;
                int col = n0 + wn + ni * 16 + lr;
                float val = acc[mi][ni][r];
                if (EPI == 0) {
                    ((_Float16*)D)[(long)b * dBatch + (long)row * N + col] = (_Float16)(val + bias[col]);
                } else if (EPI == 1) {
                    ((_Float16*)D)[(long)b * dBatch + (long)row * N + col] = (_Float16)(val + bias[row]);
                } else {
                    long idx = (long)row * N + col;
                    ((float*)D)[(long)b * dBatch + idx] =
                        val + bias[row] + resid[(long)b * rBatch + idx];
                }
            }
}

// ---------------- flash attention v11 ----------------
// r9 champion structure (i-tile 64, j-tile 32, j-split 2, XCD pinning, one
// barrier per step, PV deferred one step, parity-disjoint ps) with V moved
// from LDS to registers: vf[4] single-buffered, VLOAD(t) placed AFTER
// PV(t-1) (WAR reuse, full-step latency window), counted vmcnt(4) at the end
// barrier keeps the 4 V loads in flight while retiring the 4 K-stage loads.
// Removes 64 KB/step of LDS traffic and ALL V-read bank conflicts.
__launch_bounds__(512, 2)
__global__ void attn_kernel(const _Float16* __restrict__ qT, const _Float16* __restrict__ kT,
                            const _Float16* __restrict__ v,
                            _Float16* __restrict__ p0, _Float16* __restrict__ p1,
                            float* __restrict__ lbuf) {
    __shared__ __align__(16) _Float16 Ks[2][32 * 512];   // 64 KB, rows 1 KB, XOR (j&7)<<4
    __shared__ __align__(16) char ps[2][64 * 80];        // 10 KB, 80 B rows (conflict-free)
    __shared__ float red[8][64];
    __shared__ float redt[64];

    const int g = blockIdx.x;
    const int xcd = g & 7;
    const int comb = xcd >> 1;                       // (batch, jhalf)
    const int itile = ((g >> 3) << 1) | (xcd & 1);   // 0..63
    const int batch = comb >> 1;
    const int jhalf = comb & 1;
    const int i0 = itile * 64;
    const int jbase = jhalf * 2048;

    const int tid = threadIdx.x;
    const int l = tid & 63, w = tid >> 6;
    const int lr = l & 15, lk = l >> 4;
    const int iq = w >> 1, jq = w & 1;               // QK: rows iq*16, cols jq*16

    const _Float16* qb = qT + (long)batch * NPIX * CDIM;
    const _Float16* kb = kT + (long)batch * NPIX * CDIM;
    const _Float16* vb = v  + (long)batch * CDIM * NPIX;

    // Q fragments: rows i0 + iq*16 + lr, all 16 k-chunks (64 VGPR)
    hv8 af[16];
    {
        const _Float16* qr = qb + (long)(i0 + iq * 16 + lr) * CDIM + lk * 8;
#pragma unroll
        for (int kk = 0; kk < 16; ++kk)
            af[kk] = *(const hv8*)(qr + kk * 32);
    }

    f32x4 oacc[4][4] = {};   // rows mi*16+lk*4+r, cols w*64+ni*16+lr (AGPR)
    float lsum[4] = {};
    hv8 vf[4];               // V(t): wave-unique c-range w*64, 32 VGPR

    const _Float16* vptr = vb + (long)(w * 64 + lr) * NPIX + jbase + lk * 8;
    const float scale = 0.044194173824159216f;   // 1/sqrt(512)

// stage K tile JT (32 rows) into Ks[BUF]; 4 instrs/thread, source col pre-swizzled
#define STAGE(BUF, JT)                                                               \
    {                                                                                \
        const long j0s = (long)jbase + (JT) * 32;                                    \
        _Float16* kd = Ks[BUF];                                                      \
        _Pragma("unroll")                                                            \
        for (int q = 0; q < 4; ++q) {                                                \
            int row = q * 8 + w;                                                     \
            int cc = l ^ (row & 7);                                                  \
            lds_direct16(kb + (j0s + row) * CDIM + cc * 8, kd + row * 512);          \
        }                                                                            \
    }

// load V fragments for tile JT (4 x b128 from L2; wave-unique c-range)
#define VLOAD(JT)                                                                    \
    {                                                                                \
        _Pragma("unroll")                                                            \
        for (int ni = 0; ni < 4; ++ni)                                               \
            vf[ni] = *(const hv8*)(vptr + (long)ni * (16 * NPIX) + (JT) * 32);       \
    }

// QK(JT) -> exp -> ps[CUR]
#define QKEXP(CUR)                                                                   \
    {                                                                                \
        const char* kbase = (const char*)Ks[CUR];                                    \
        f32x4 sa = {}, sb = {};                                                      \
        const int jj = jq * 16 + lr;                                                 \
        const uint32_t sw = (uint32_t)((jj & 7) << 4);                               \
        _Pragma("unroll")                                                            \
        for (int kk = 0; kk < 8; ++kk) {                                             \
            hv8 b0 = *(const hv8*)(kbase + (((uint32_t)(jj * 1024 + (2 * kk) * 64 + lk * 16)) ^ sw));     \
            sa = __builtin_amdgcn_mfma_f32_16x16x32_f16(af[2 * kk], b0, sa, 0, 0, 0);                     \
            hv8 b1 = *(const hv8*)(kbase + (((uint32_t)(jj * 1024 + (2 * kk + 1) * 64 + lk * 16)) ^ sw)); \
            sb = __builtin_amdgcn_mfma_f32_16x16x32_f16(af[2 * kk + 1], b1, sb, 0, 0, 0);                 \
        }                                                                            \
        sa += sb;                                                                    \
        _Pragma("unroll")                                                            \
        for (int r = 0; r < 4; ++r) {                                                \
            float p = __expf(sa[r] * scale);                                         \
            lsum[r] += p;                                                            \
            int i = iq * 16 + lk * 4 + r;                                            \
            int j2 = jq * 16 + lr;                                                   \
            *(_Float16*)(ps[CUR] + i * 80 + j2 * 2) = (_Float16)p;                   \
        }                                                                            \
    }

// PV of the PREVIOUS step: ps[PRV] x vf (holding V(t-1))
#define PVSTEP(PRV)                                                                  \
    {                                                                                \
        _Pragma("unroll")                                                            \
        for (int mi = 0; mi < 4; ++mi) {                                             \
            int i2 = mi * 16 + lr;                                                   \
            hv8 pa = *(const hv8*)(ps[PRV] + i2 * 80 + lk * 16);                     \
            _Pragma("unroll")                                                        \
            for (int ni = 0; ni < 4; ++ni)                                           \
                oacc[mi][ni] = __builtin_amdgcn_mfma_f32_16x16x32_f16(pa, vf[ni], oacc[mi][ni], 0, 0, 0); \
        }                                                                            \
    }

// counted end barrier: retires the 4 K-stage loads, keeps the 4 V loads in flight
#define ENDBAR(N)                                                                    \
    __builtin_amdgcn_sched_barrier(0);                                               \
    asm volatile("s_waitcnt vmcnt(" #N ") lgkmcnt(0)" ::: "memory");                 \
    __builtin_amdgcn_s_barrier();                                                    \
    __builtin_amdgcn_sched_barrier(0);

// CUR = compile-time parity of JT (passed as literal).
#define STEP(JT, CUR)                                                                \
    {                                                                                \
        if ((JT) < 63) STAGE((CUR) ^ 1, (JT) + 1)                                    \
        __builtin_amdgcn_sched_barrier(0);                                           \
        __builtin_amdgcn_s_setprio(1);                                               \
        QKEXP(CUR)                                                                   \
        PVSTEP((CUR) ^ 1)                                                            \
        __builtin_amdgcn_s_setprio(0);                                               \
        __builtin_amdgcn_sched_barrier(0);                                           \
        VLOAD(JT)                                                                    \
        ENDBAR(4)                                                                    \
    }

    // prologue: K(0) staged and drained
    STAGE(0, 0)
    __builtin_amdgcn_sched_barrier(0);
    asm volatile("s_waitcnt vmcnt(0)" ::: "memory");
    __builtin_amdgcn_s_barrier();
    __builtin_amdgcn_sched_barrier(0);

    // step 0: no PV yet; V(0) loaded after QK
    STAGE(1, 1)
    __builtin_amdgcn_s_setprio(1);
    QKEXP(0)
    __builtin_amdgcn_s_setprio(0);
    VLOAD(0)
    ENDBAR(4)

    // steady: steps 1..62 in pairs, then 63
    for (int jt = 1; jt < 63; jt += 2) {
        STEP(jt,     1)
        STEP(jt + 1, 0)
    }
    STEP(63, 1)

    // epilogue: PV(63) -- drain the last V loads first
    asm volatile("s_waitcnt vmcnt(0)" ::: "memory");
    __builtin_amdgcn_sched_barrier(0);
    PVSTEP(1)

    // ---- row-sum reduce: over lr (16 lanes), then over the jq wave-pair ----
#pragma unroll
    for (int m = 1; m <= 8; m <<= 1)
#pragma unroll
        for (int r = 0; r < 4; ++r)
            lsum[r] += __shfl_xor(lsum[r], m, 64);
    if (lr == 0)
#pragma unroll
        for (int r = 0; r < 4; ++r)
            red[w][iq * 16 + lk * 4 + r] = lsum[r];
    __syncthreads();
    if (tid < 64) {
        int iq2 = tid >> 4;
        float lv = red[iq2 * 2][tid] + red[iq2 * 2 + 1][tid];
        redt[tid] = 1.0f / lv;
        lbuf[jhalf * 8192 + batch * NPIX + i0 + tid] = lv;
    }
    __syncthreads();

    // ---- store normalized per-half partial O (fp16) ----
    _Float16* dsth = (jhalf ? p1 : p0) + (long)batch * NPIX * CDIM;
#pragma unroll
    for (int mi = 0; mi < 4; ++mi)
#pragma unroll
        for (int r = 0; r < 4; ++r) {
            int row = mi * 16 + lk * 4 + r;
            float rv = redt[row];
#pragma unroll
            for (int ni = 0; ni < 4; ++ni) {
                int c = w * 64 + ni * 16 + lr;
                dsth[(long)(i0 + row) * CDIM + c] = (_Float16)(oacc[mi][ni][r] * rv);
            }
        }
#undef STEP
#undef ENDBAR
#undef PVSTEP
#undef QKEXP
#undef VLOAD
#undef STAGE
}

// ---------------- combine: out = (O0*l0 + O1*l1) / (l0+l1) ----------------
__global__ void combine_kernel(const _Float16* __restrict__ p0, const _Float16* __restrict__ p1,
                               const float* __restrict__ lbuf, _Float16* __restrict__ out) {
    long g = (long)blockIdx.x * 256 + threadIdx.x;
    long base = g * 8;
    int rowg = (int)(g >> 6);                 // b*4096 + n
    float l0 = lbuf[rowg], l1 = lbuf[8192 + rowg];
    float w0 = l0 / (l0 + l1);
    float w1 = 1.0f - w0;
    hv8 a = *(const hv8*)(p0 + base);
    hv8 b = *(const hv8*)(p1 + base);
    hv8 o;
#pragma unroll
    for (int i = 0; i < 8; ++i)
        o[i] = (_Float16)((float)a[i] * w0 + (float)b[i] * w1);
    *(hv8*)(out + base) = o;
}

extern "C" void kernel_launch(void* const* d_in, const int* in_sizes, int n_in,
                              void* d_out, int out_size, void* d_ws, size_t ws_size,
                              hipStream_t stream) {
    const float* x     = (const float*)d_in[0];
    const float* gamma = (const float*)d_in[1];
    const float* beta  = (const float*)d_in[2];
    const float* wq    = (const float*)d_in[3];
    const float* bq    = (const float*)d_in[4];
    const float* wk    = (const float*)d_in[5];
    const float* bk    = (const float*)d_in[6];
    const float* wv    = (const float*)d_in[7];
    const float* bv    = (const float*)d_in[8];
    const float* wo    = (const float*)d_in[9];
    const float* bo    = (const float*)d_in[10];
    float* out = (float*)d_out;

    char* ws = (char*)d_ws;
    float* stats = (float*)ws;
    _Float16* wqb = (_Float16*)(ws + 1024);
    _Float16* wkb = wqb + 262144;
    _Float16* wvb = wkb + 262144;
    _Float16* wob = wvb + 262144;
    _Float16* hT  = wob + 262144;
    const long TSZ = (long)2 * NPIX * CDIM;
    _Float16* qT = hT + TSZ;
    _Float16* kT = qT + TSZ;
    _Float16* vv = kT + TSZ;
    _Float16* oT = vv + TSZ;
    float* lbuf = (float*)(oT + TSZ);        // 2 halves x 8192 rows

    cvt_w<<<dim3(1024), dim3(256), 0, stream>>>(wq, wk, wv, wo, wqb, wkb, wvb, wob);
    stats_kernel<<<dim3(64), dim3(256), 0, stream>>>(x, stats);
    normT_kernel<<<dim3(16, 128, 2), dim3(256), 0, stream>>>(x, stats, gamma, beta, hT);

    const long NC = (long)NPIX * CDIM;
    gemm_bt_kernel<0><<<dim3(4, 32, 2), dim3(256), 0, stream>>>(
        hT, wqb, (void*)qT, bq, nullptr, NPIX, CDIM, CDIM, NC, 0L, NC, 0L);
    gemm_bt_kernel<0><<<dim3(4, 32, 2), dim3(256), 0, stream>>>(
        hT, wkb, (void*)kT, bk, nullptr, NPIX, CDIM, CDIM, NC, 0L, NC, 0L);
    gemm_bt_kernel<1><<<dim3(32, 4, 2), dim3(256), 0, stream>>>(
        wvb, hT, (void*)vv, bv, nullptr, CDIM, NPIX, CDIM, 0L, NC, NC, 0L);

    // attention: partial jhalf0 -> oT, jhalf1 -> hT (dead), sums -> lbuf
    attn_kernel<<<dim3(256), dim3(512), 0, stream>>>(qT, kT, vv, oT, hT, lbuf);

    // combine halves into qT (dead after attn)
    combine_kernel<<<dim3(2048), dim3(256), 0, stream>>>(oT, hT, lbuf, qT);

    gemm_bt_kernel<2><<<dim3(32, 4, 2), dim3(256), 0, stream>>>(
        wob, qT, (void*)out, bo, x, CDIM, NPIX, CDIM, 0L, NC, NC, NC);
}